// Round 8
// baseline (44.176 us; speedup 1.0000x reference)
//
#include <hip/hip_runtime.h>
#include <math.h>

typedef _Float16 half8 __attribute__((ext_vector_type(8)));
typedef float f32x16 __attribute__((ext_vector_type(16)));

#define DIMK 2048
#define NEXP 64
#define BM 32                 // rows per block
#define NW 4                  // waves per block (k-split)
#define KPW (DIMK / NW)       // 512 k per wave
#define CHUNK 32              // k per staged chunk/region (2 ksteps)
#define NCHUNK (KPW / CHUNK)  // 16 regions per wave
#define KSTEP 16              // k per 32x32x16 MFMA step
#define NKS (CHUNK / KSTEP)   // 2 ksteps per region

__device__ __forceinline__ bool gt_pair(float v, int i, float v2, int i2) {
    return (v > v2) || (v == v2 && i < i2);
}

__global__ __launch_bounds__(256, 3)
void SwitchRouter_43078521979510_kernel(const float* __restrict__ x,
                                        const float* __restrict__ W,
                                        const float* __restrict__ bias,
                                        float* __restrict__ out, int M)
{
    __shared__ float lds[8704];   // 34.8 KB: 4 waves x dbuf x (32 rows x 32 k); aliased by reduction

    const int t     = threadIdx.x;
    const int wv    = t >> 6;
    const int lane  = t & 63;
    const int row   = lane & 31;   // A row within tile / W expert within et-group
    const int half_ = lane >> 5;   // k sub-slice selector
    const int r0    = blockIdx.x * BM;
    const int kwb   = wv * KPW;

    float* atile = lds + wv * 2048;     // 2 bufs x 1024 floats
    const float* xg0 = x + (size_t)r0 * DIMK + kwb;
    // W fragment source (fp32): expert = et*32+row, k = kwb + u*16 + half_*8 + j
    const float* wbase0 = W + (size_t)row * DIMK + kwb + half_ * 8;

    // A staging (R7-validated): instr j covers rows j*8+(lane>>3), granule lane&7 XOR row&7
#define STAGE(c)                                                                   \
    {                                                                              \
        float* dst = atile + ((c) & 1) * 1024;                                     \
        _Pragma("unroll") for (int j = 0; j < 4; ++j) {                            \
            const int rowj = j * 8 + (lane >> 3);                                  \
            const float* src = xg0 + (size_t)rowj * DIMK + (c) * CHUNK             \
                               + (((lane & 7) ^ (rowj & 7)) << 2);                 \
            __builtin_amdgcn_global_load_lds(                                      \
                (const __attribute__((address_space(1))) void*)src,                \
                (__attribute__((address_space(3))) void*)(dst + j * 256),          \
                16, 0, 0);                                                         \
        }                                                                          \
    }

    // W region load: both ksteps of region c2 into ring slot (8 x dwordx4)
#define LOADW2(c2, slot)                                                           \
    {                                                                              \
        _Pragma("unroll") for (int ks2 = 0; ks2 < 2; ++ks2)                        \
        _Pragma("unroll") for (int et = 0; et < 2; ++et)                           \
        _Pragma("unroll") for (int h = 0; h < 2; ++h)                              \
            wring[slot][ks2][et][h] = *(const float4*)(wbase0                      \
                + (size_t)et * 32 * DIMK + ((c2) * CHUNK + ks2 * KSTEP + h * 4));  \
    }

    // convert fp32 W kstep -> f16 limb fragments (hi w0, residual w1)
#define CONVW(slot, ks2)                                                           \
    {                                                                              \
        _Pragma("unroll") for (int et = 0; et < 2; ++et) {                         \
            const float4 va = wring[slot][ks2][et][0], vb = wring[slot][ks2][et][1]; \
            const float f[8] = {va.x, va.y, va.z, va.w, vb.x, vb.y, vb.z, vb.w};   \
            _Pragma("unroll") for (int j = 0; j < 8; ++j) {                        \
                _Float16 h = (_Float16)f[j];                                       \
                w0[et][j] = h;                                                     \
                w1[et][j] = (_Float16)(f[j] - (float)h);                           \
            }                                                                      \
        }                                                                          \
    }

#define DOMFMA()                                                                   \
    {                                                                              \
        acc[0] = __builtin_amdgcn_mfma_f32_32x32x16_f16(a0, w0[0], acc[0], 0, 0, 0); \
        acc[0] = __builtin_amdgcn_mfma_f32_32x32x16_f16(a1, w0[0], acc[0], 0, 0, 0); \
        acc[0] = __builtin_amdgcn_mfma_f32_32x32x16_f16(a0, w1[0], acc[0], 0, 0, 0); \
        acc[1] = __builtin_amdgcn_mfma_f32_32x32x16_f16(a0, w0[1], acc[1], 0, 0, 0); \
        acc[1] = __builtin_amdgcn_mfma_f32_32x32x16_f16(a1, w0[1], acc[1], 0, 0, 0); \
        acc[1] = __builtin_amdgcn_mfma_f32_32x32x16_f16(a0, w1[1], acc[1], 0, 0, 0); \
    }

#define CONVA(ks2)                                                                 \
    {                                                                              \
        const float4 va = fA[ks2], vb = fB[ks2];                                   \
        const float f[8] = {va.x, va.y, va.z, va.w, vb.x, vb.y, vb.z, vb.w};       \
        _Pragma("unroll") for (int j = 0; j < 8; ++j) {                            \
            _Float16 h = (_Float16)f[j];                                           \
            a0[j] = h;                                                             \
            a1[j] = (_Float16)(f[j] - (float)h);                                   \
        }                                                                          \
    }

    float4 wring[2][2][2][2];   // [slot][kstep][et][half]: 64 VGPR, all indices static
    f32x16 acc[2] = {};         // one accumulator per 32-expert tile

    // prologue issue order fixes the vmcnt ledger: W2(0)[8], W2(1)[8], A(0)[4], A(1)[4]
    LOADW2(0, 0);
    LOADW2(1, 1);
    STAGE(0);
    STAGE(1);

    // chunk-pair loop keeps ring slot (c&1) and dbuf index compile-time static
    for (int cb = 0; cb < NCHUNK / 2; ++cb) {
#pragma unroll
        for (int pc = 0; pc < 2; ++pc) {
            const int c = 2 * cb + pc;              // c & 1 == pc (static)
            // fence: retire W2(c) + STAGE(c).
            // region 0: outstanding = W2(0),W2(1),S(0),S(1); need W2(0),S(0) -> leave S(1) = 4.
            // steady:   younger-than-S(c) = S(c+1)[4] + W2(c+1)[8] = 12.
            // last:     drain all.
            if (cb == 0 && pc == 0) {
                asm volatile("s_waitcnt vmcnt(4)" ::: "memory");
            } else if (cb == NCHUNK / 2 - 1 && pc == 1) {
                asm volatile("s_waitcnt vmcnt(0)" ::: "memory");
            } else {
                asm volatile("s_waitcnt vmcnt(12)" ::: "memory");
            }

            const float* buf = atile + pc * 1024;

            // ---- hoisted A-fragment ds_reads for both ksteps (XOR-swizzled granules) ----
            float4 fA[NKS], fB[NKS];
#pragma unroll
            for (int ks = 0; ks < NKS; ++ks) {
                const int g  = ks * 4 + half_ * 2;
                const int s0 = g ^ (row & 7);
                const int s1 = (g + 1) ^ (row & 7);
                fA[ks] = *(const float4*)&buf[row * 32 + s0 * 4];
                fB[ks] = *(const float4*)&buf[row * 32 + s1 * 4];
            }

            half8 w0[2], w1[2], a0, a1;

            // convert W kstep0 while ds_reads are in flight
            CONVW(pc, 0);

            // A buffer captured -> safe to restage this buffer
            asm volatile("s_waitcnt lgkmcnt(0)" ::: "memory");
            if (c + 2 < NCHUNK) STAGE(c + 2);

            // kstep 0: MFMAs (W slot kstep0 now consumed)
            CONVA(0);
            DOMFMA();

            // convert W kstep1 -> slot fully consumed; reissue ring slot for region c+2
            CONVW(pc, 1);
            if (c + 2 < NCHUNK) LOADW2(c + 2, pc);

            // kstep 1: MFMAs
            CONVA(1);
            DOMFMA();
        }
    }

    // ---------------- cross-wave K reduction (R2-validated) ----------------
    __syncthreads();
    float* red = lds;   // [wave][32 rows][68 pad] = 4 x 2176 floats
    // D frag (32x32): col = lane&31, rowD = (s&3) + 8*(s>>2) + 4*half_
#pragma unroll
    for (int s = 0; s < 16; ++s) {
        const int rowD = (s & 3) + 8 * (s >> 2) + 4 * half_;
        red[wv * 2176 + rowD * 68 + 0 * 32 + row] = acc[0][s];
        red[wv * 2176 + rowD * 68 + 1 * 32 + row] = acc[1][s];
    }
    __syncthreads();

    // ---------------- epilogue: bias + stable top-2 + softmax (validated path) ----------------
    {
        const int rr = t >> 3;   // 0..31 row within block
        const int g8 = t & 7;    // expert-group 0..7
        float l[8];
#pragma unroll
        for (int j = 0; j < 8; ++j) {
            float s = 0.f;
#pragma unroll
            for (int w2 = 0; w2 < NW; ++w2) s += red[w2 * 2176 + rr * 68 + g8 * 8 + j];
            l[j] = s + bias[g8 * 8 + j];
        }

        float v0 = l[0];
        int   i0 = 8 * g8;
        float v1 = -INFINITY;
        int   i1 = -1;
#pragma unroll
        for (int j = 1; j < 8; ++j) {
            const float lv = l[j];
            const int   e  = 8 * g8 + j;
            if (lv > v0) { v1 = v0; i1 = i0; v0 = lv; i0 = e; }
            else if (lv > v1) { v1 = lv; i1 = e; }
        }
#pragma unroll
        for (int m2 = 1; m2 <= 4; m2 <<= 1) {
            const float ov0 = __shfl_xor(v0, m2);
            const int   oi0 = __shfl_xor(i0, m2);
            const float ov1 = __shfl_xor(v1, m2);
            const int   oi1 = __shfl_xor(i1, m2);
            if (gt_pair(ov0, oi0, v0, i0)) {
                if (gt_pair(v0, i0, ov1, oi1)) { v1 = v0; i1 = i0; }
                else                           { v1 = ov1; i1 = oi1; }
                v0 = ov0; i0 = oi0;
            } else if (gt_pair(ov0, oi0, v1, i1)) {
                v1 = ov0; i1 = oi0;
            }
        }
        float d = 0.f;
#pragma unroll
        for (int j = 0; j < 8; ++j) d += expf(l[j] - v0);
#pragma unroll
        for (int m2 = 1; m2 <= 4; m2 <<= 1) d += __shfl_xor(d, m2);

        if (g8 == 0) {
            const int R = r0 + rr;
            out[2 * R]     = (float)i0;
            out[2 * R + 1] = (float)i1;
            out[2 * M + 2 * R]     = 1.f / d;
            out[2 * M + 2 * R + 1] = expf(v1 - v0) / d;
        }
    }
}

extern "C" void kernel_launch(void* const* d_in, const int* in_sizes, int n_in,
                              void* d_out, int out_size, void* d_ws, size_t ws_size,
                              hipStream_t stream) {
    const float* x  = (const float*)d_in[0];
    const float* W  = (const float*)d_in[1];
    const float* b  = (const float*)d_in[2];
    float* out = (float*)d_out;
    const int M = in_sizes[0] / DIMK;   // 16384 rows
    SwitchRouter_43078521979510_kernel<<<M / BM, 256, 0, stream>>>(x, W, b, out, M);
}

// Round 9
// 40.648 us; speedup vs baseline: 1.0868x; 1.0868x over previous
//
#include <hip/hip_runtime.h>
#include <math.h>

typedef _Float16 half8 __attribute__((ext_vector_type(8)));
typedef float f32x16 __attribute__((ext_vector_type(16)));

#define DIMK 2048
#define NEXP 64
#define BM 32                 // rows per block
#define NW 8                  // waves per block (k-split)
#define KPW (DIMK / NW)       // 256 k per wave
#define CHUNK 32              // k per staged region (2 ksteps)
#define NCHUNK (KPW / CHUNK)  // 8 regions per wave
#define KSTEP 16              // k per 32x32x16 MFMA step

// ---------------- W pre-split kernel (R2/R7-validated) ----------------
// ws layout (halfs): [kb8 = k/8][limb][e][k%8]  -> block of 512 halfs per (kb8,limb)
__global__ void SwitchRouter_wsplit(const float* __restrict__ W, _Float16* __restrict__ ws) {
    int t = blockIdx.x * 256 + threadIdx.x;
    if (t >= NEXP * DIMK) return;
    int e = t >> 11, k = t & (DIMK - 1);
    float w = W[e * DIMK + k];
    _Float16 h0 = (_Float16)w;
    _Float16 h1 = (_Float16)(w - (float)h0);
    int kb8 = k >> 3, kj = k & 7;
    ws[(((kb8 * 2 + 0) << 9) + (e << 3) + kj)] = h0;
    ws[(((kb8 * 2 + 1) << 9) + (e << 3) + kj)] = h1;
}

__device__ __forceinline__ bool gt_pair(float v, int i, float v2, int i2) {
    return (v > v2) || (v == v2 && i < i2);
}

__device__ __forceinline__ half8 ldw(const _Float16* wsp, int kglob0, int half_, int et, int limb, int row) {
    int kb8 = (kglob0 >> 3) + half_;
    return *(const half8*)(wsp + (((size_t)(kb8 * 2 + limb) << 9) + (((et << 5) + row) << 3)));
}

__global__ __launch_bounds__(512, 4)
void SwitchRouter_43078521979510_kernel(const float* __restrict__ x,
                                        const _Float16* __restrict__ wsp,
                                        const float* __restrict__ bias,
                                        float* __restrict__ out, int M)
{
    __shared__ float lds[16384];   // 64 KB: 8 waves x dbuf x (32 rows x 32 k fp32); aliased by reduction

    const int t     = threadIdx.x;
    const int wv    = t >> 6;
    const int lane  = t & 63;
    const int row   = lane & 31;   // A row within tile / W expert within et-group
    const int half_ = lane >> 5;   // k sub-slice selector
    const int r0    = blockIdx.x * BM;
    const int kwb   = wv * KPW;

    float* atile = lds + wv * 2048;     // 2 bufs x 1024 floats
    const float* xg0 = x + (size_t)r0 * DIMK + kwb;

    // A staging (R7-validated): instr j covers rows j*8+(lane>>3), granule lane&7 XOR row&7
#define STAGE(c)                                                                   \
    {                                                                              \
        float* dst = atile + ((c) & 1) * 1024;                                     \
        _Pragma("unroll") for (int j = 0; j < 4; ++j) {                            \
            const int rowj = j * 8 + (lane >> 3);                                  \
            const float* src = xg0 + (size_t)rowj * DIMK + (c) * CHUNK             \
                               + (((lane & 7) ^ (rowj & 7)) << 2);                 \
            __builtin_amdgcn_global_load_lds(                                      \
                (const __attribute__((address_space(1))) void*)src,                \
                (__attribute__((address_space(3))) void*)(dst + j * 256),          \
                16, 0, 0);                                                         \
        }                                                                          \
    }

#define LOADW(u, slot)                                                             \
    {                                                                              \
        const int kg = kwb + (u) * KSTEP;                                          \
        wr[slot][0] = ldw(wsp, kg, half_, 0, 0, row);                              \
        wr[slot][1] = ldw(wsp, kg, half_, 0, 1, row);                              \
        wr[slot][2] = ldw(wsp, kg, half_, 1, 0, row);                              \
        wr[slot][3] = ldw(wsp, kg, half_, 1, 1, row);                              \
    }

    // ds_reads for both ksteps of buffer pc (XOR-swizzled granules) + lgkm drain
#define DSRD(pc)                                                                   \
    {                                                                              \
        const float* buf = atile + (pc) * 1024;                                    \
        _Pragma("unroll") for (int ks = 0; ks < 2; ++ks) {                         \
            const int g = ks * 4 + half_ * 2;                                      \
            fA[ks] = *(const float4*)&buf[row * 32 + ((g ^ (row & 7)) << 2)];      \
            fB[ks] = *(const float4*)&buf[row * 32 + (((g + 1) ^ (row & 7)) << 2)];\
        }                                                                          \
        asm volatile("s_waitcnt lgkmcnt(0)" ::: "memory");                         \
    }

#define KS(ks, slot)                                                               \
    {                                                                              \
        const float4 va = fA[ks], vb = fB[ks];                                     \
        const float f[8] = {va.x, va.y, va.z, va.w, vb.x, vb.y, vb.z, vb.w};       \
        half8 a0, a1;                                                              \
        _Pragma("unroll") for (int j = 0; j < 8; ++j) {                            \
            _Float16 h = (_Float16)f[j];                                           \
            a0[j] = h;                                                             \
            a1[j] = (_Float16)(f[j] - (float)h);                                   \
        }                                                                          \
        acc[0] = __builtin_amdgcn_mfma_f32_32x32x16_f16(a0, wr[slot][0], acc[0], 0, 0, 0); \
        acc[0] = __builtin_amdgcn_mfma_f32_32x32x16_f16(a1, wr[slot][0], acc[0], 0, 0, 0); \
        acc[0] = __builtin_amdgcn_mfma_f32_32x32x16_f16(a0, wr[slot][1], acc[0], 0, 0, 0); \
        acc[1] = __builtin_amdgcn_mfma_f32_32x32x16_f16(a0, wr[slot][2], acc[1], 0, 0, 0); \
        acc[1] = __builtin_amdgcn_mfma_f32_32x32x16_f16(a1, wr[slot][2], acc[1], 0, 0, 0); \
        acc[1] = __builtin_amdgcn_mfma_f32_32x32x16_f16(a0, wr[slot][3], acc[1], 0, 0, 0); \
    }

    half8 wr[2][4];       // W ring: 2 slots x (2 limbs x 2 expert-tiles), static indices
    float4 fA[2], fB[2];
    f32x16 acc[2] = {};   // one accumulator per 32-expert tile

    // prologue queue: W0[4], W1[4], S0[4], S1[4]
    LOADW(0, 0); LOADW(1, 1);
    STAGE(0); STAGE(1);

    // ---- region 0 (buf0) ----
    asm volatile("s_waitcnt vmcnt(4)" ::: "memory");   // retire W0,W1,S0; leave S1
    DSRD(0);
    STAGE(2);
    KS(0, 0); LOADW(2, 0);                             // W0 already fenced
    KS(1, 1); LOADW(3, 1);                             // W1 already fenced

    // ---- region 1 (buf1) ----
    asm volatile("s_waitcnt vmcnt(12)" ::: "memory");  // retire S1; leave S2,W2,W3
    DSRD(1);
    STAGE(3);
    asm volatile("s_waitcnt vmcnt(8)" ::: "memory");   // retire S2,W2; leave W3,S3
    KS(0, 0); LOADW(4, 0);
    asm volatile("s_waitcnt vmcnt(8)" ::: "memory");   // retire W3; leave S3,W4
    KS(1, 1); LOADW(5, 1);

    // ---- regions 2..5 (S(c) retired by F0@(c-1); buffers static) ----
    for (int cb = 1; cb <= 2; ++cb) {
        const int c0 = 2 * cb;                         // 2 or 4
        // region c0 (buf0)
        DSRD(0);
        STAGE(c0 + 2);
        asm volatile("s_waitcnt vmcnt(8)" ::: "memory");
        KS(0, 0); LOADW(2 * c0 + 2, 0);
        asm volatile("s_waitcnt vmcnt(8)" ::: "memory");
        KS(1, 1); LOADW(2 * c0 + 3, 1);
        // region c0+1 (buf1)
        DSRD(1);
        STAGE(c0 + 3);
        asm volatile("s_waitcnt vmcnt(8)" ::: "memory");
        KS(0, 0); LOADW(2 * c0 + 4, 0);
        asm volatile("s_waitcnt vmcnt(8)" ::: "memory");
        KS(1, 1); LOADW(2 * c0 + 5, 1);
    }

    // ---- region 6 (buf0, no STAGE) ----
    DSRD(0);
    asm volatile("s_waitcnt vmcnt(4)" ::: "memory");   // retire S7,W12; leave W13
    KS(0, 0); LOADW(14, 0);
    asm volatile("s_waitcnt vmcnt(4)" ::: "memory");   // retire W13; leave W14
    KS(1, 1); LOADW(15, 1);

    // ---- region 7 (buf1, no STAGE, no LOADW) ----
    DSRD(1);
    asm volatile("s_waitcnt vmcnt(4)" ::: "memory");   // retire W14; leave W15
    KS(0, 0);
    asm volatile("s_waitcnt vmcnt(0)" ::: "memory");
    KS(1, 1);

    // ---------------- cross-wave K reduction (R5-validated pairwise tree, 8->1) ----------------
    __syncthreads();
    float* red = lds;   // 4 slots x [32 rows][68 pad] = 8704 floats (aliases atile space)
    // D frag (32x32): col = lane&31 (expert within et-tile), rowD = (s&3)+8*(s>>2)+4*half_

#define TILE_STORE(slot)                                                           \
    {                                                                              \
        _Pragma("unroll") for (int et = 0; et < 2; ++et)                           \
        _Pragma("unroll") for (int s = 0; s < 16; ++s) {                           \
            const int rowD = (s & 3) + 8 * (s >> 2) + 4 * half_;                   \
            red[(slot) * 2176 + rowD * 68 + et * 32 + row] = acc[et][s];           \
        }                                                                          \
    }
#define TILE_ADD(slot)                                                             \
    {                                                                              \
        _Pragma("unroll") for (int et = 0; et < 2; ++et)                           \
        _Pragma("unroll") for (int s = 0; s < 16; ++s) {                           \
            const int rowD = (s & 3) + 8 * (s >> 2) + 4 * half_;                   \
            acc[et][s] += red[(slot) * 2176 + rowD * 68 + et * 32 + row];          \
        }                                                                          \
    }

    if (wv & 1) TILE_STORE(wv >> 1);              // waves 1,3,5,7 -> slots 0..3
    __syncthreads();
    if (!(wv & 1)) TILE_ADD(wv >> 1);             // waves 0,2,4,6 absorb partners
    __syncthreads();
    if (wv == 2 || wv == 6) TILE_STORE(wv >> 2);  // -> slots 0,1
    __syncthreads();
    if (wv == 0 || wv == 4) TILE_ADD(wv >> 2);
    __syncthreads();
    if (wv == 4) TILE_STORE(0);
    __syncthreads();
    if (wv == 0) {
        TILE_ADD(0);
        // final logits (no bias) -> slot 0
#pragma unroll
        for (int et = 0; et < 2; ++et)
#pragma unroll
            for (int s = 0; s < 16; ++s) {
                const int rowD = (s & 3) + 8 * (s >> 2) + 4 * half_;
                red[rowD * 68 + et * 32 + row] = acc[et][s];
            }
    }
    __syncthreads();

    // ---------------- epilogue: bias + stable top-2 + softmax (validated path) ----------------
    if (t < BM * 8) {
        const int rr = t >> 3;   // 0..31 row within block
        const int g8 = t & 7;    // expert-group 0..7
        float l[8];
#pragma unroll
        for (int j = 0; j < 8; ++j)
            l[j] = red[rr * 68 + g8 * 8 + j] + bias[g8 * 8 + j];

        float v0 = l[0];
        int   i0 = 8 * g8;
        float v1 = -INFINITY;
        int   i1 = -1;
#pragma unroll
        for (int j = 1; j < 8; ++j) {
            const float lv = l[j];
            const int   e  = 8 * g8 + j;
            if (lv > v0) { v1 = v0; i1 = i0; v0 = lv; i0 = e; }
            else if (lv > v1) { v1 = lv; i1 = e; }
        }
#pragma unroll
        for (int m2 = 1; m2 <= 4; m2 <<= 1) {
            const float ov0 = __shfl_xor(v0, m2);
            const int   oi0 = __shfl_xor(i0, m2);
            const float ov1 = __shfl_xor(v1, m2);
            const int   oi1 = __shfl_xor(i1, m2);
            if (gt_pair(ov0, oi0, v0, i0)) {
                if (gt_pair(v0, i0, ov1, oi1)) { v1 = v0; i1 = i0; }
                else                           { v1 = ov1; i1 = oi1; }
                v0 = ov0; i0 = oi0;
            } else if (gt_pair(ov0, oi0, v1, i1)) {
                v1 = ov0; i1 = oi0;
            }
        }
        float d = 0.f;
#pragma unroll
        for (int j = 0; j < 8; ++j) d += expf(l[j] - v0);
#pragma unroll
        for (int m2 = 1; m2 <= 4; m2 <<= 1) d += __shfl_xor(d, m2);

        if (g8 == 0) {
            const int R = r0 + rr;
            out[2 * R]     = (float)i0;
            out[2 * R + 1] = (float)i1;
            out[2 * M + 2 * R]     = 1.f / d;
            out[2 * M + 2 * R + 1] = expf(v1 - v0) / d;
        }
    }
}

extern "C" void kernel_launch(void* const* d_in, const int* in_sizes, int n_in,
                              void* d_out, int out_size, void* d_ws, size_t ws_size,
                              hipStream_t stream) {
    const float* x  = (const float*)d_in[0];
    const float* W  = (const float*)d_in[1];
    const float* b  = (const float*)d_in[2];
    float* out = (float*)d_out;
    _Float16* ws = (_Float16*)d_ws;
    const int M = in_sizes[0] / DIMK;   // 16384 rows

    SwitchRouter_wsplit<<<(NEXP * DIMK + 255) / 256, 256, 0, stream>>>(W, ws);
    SwitchRouter_43078521979510_kernel<<<M / BM, 512, 0, stream>>>(x, ws, b, out, M);
}

// Round 11
// 33.966 us; speedup vs baseline: 1.3006x; 1.1967x over previous
//
#include <hip/hip_runtime.h>
#include <math.h>

typedef _Float16 half8 __attribute__((ext_vector_type(8)));
typedef float f32x16 __attribute__((ext_vector_type(16)));

#define DIMK 2048
#define NEXP 64
#define BM 32                 // rows per block
#define NW 4                  // waves per block (k-split)
#define KPW (DIMK / NW)       // 512 k per wave
#define CHUNK 32              // k per staged chunk (2 ksteps)
#define NCHUNK (KPW / CHUNK)  // 16 chunks per wave
#define KSTEP 16              // k per 32x32x16 MFMA step
#define NKS (CHUNK / KSTEP)   // 2 ksteps per chunk
#define NU (KPW / KSTEP)      // 32 ksteps total per wave

// ---------------- W pre-split kernel (R2-validated) ----------------
// ws layout (halfs): [kb8 = k/8][limb][e][k%8]  -> block of 512 halfs per (kb8,limb)
__global__ void SwitchRouter_wsplit(const float* __restrict__ W, _Float16* __restrict__ ws) {
    int t = blockIdx.x * 256 + threadIdx.x;
    if (t >= NEXP * DIMK) return;
    int e = t >> 11, k = t & (DIMK - 1);
    float w = W[e * DIMK + k];
    _Float16 h0 = (_Float16)w;
    _Float16 h1 = (_Float16)(w - (float)h0);
    int kb8 = k >> 3, kj = k & 7;
    ws[(((kb8 * 2 + 0) << 9) + (e << 3) + kj)] = h0;
    ws[(((kb8 * 2 + 1) << 9) + (e << 3) + kj)] = h1;
}

__device__ __forceinline__ bool gt_pair(float v, int i, float v2, int i2) {
    return (v > v2) || (v == v2 && i < i2);
}

__device__ __forceinline__ half8 ldw(const _Float16* wsp, int kglob0, int half_, int et, int limb, int row) {
    int kb8 = (kglob0 >> 3) + half_;
    return *(const half8*)(wsp + (((size_t)(kb8 * 2 + limb) << 9) + (((et << 5) + row) << 3)));
}

__global__ __launch_bounds__(256, 3)
void SwitchRouter_43078521979510_kernel(const float* __restrict__ x,
                                        const _Float16* __restrict__ wsp,
                                        const float* __restrict__ bias,
                                        float* __restrict__ out, int M)
{
    __shared__ float lds[8704];   // 34.8 KB: 4 waves x dbuf x (32 rows x 32 k); aliased by reduction (4x2176)

    const int t     = threadIdx.x;
    const int wv    = t >> 6;
    const int lane  = t & 63;
    const int row   = lane & 31;   // A row within tile / W expert within et-group
    const int half_ = lane >> 5;   // k sub-slice selector
    const int r0    = blockIdx.x * BM;
    const int kwb   = wv * KPW;

    float* atile = lds + wv * 2048;     // 2 bufs x 1024 floats
    const float* xg0 = x + (size_t)r0 * DIMK + kwb;

    // staging: instr j covers rows j*8+(lane>>3), granule lane&7 (XOR-swizzled vs row&7)
#define STAGE(c)                                                                   \
    {                                                                              \
        float* dst = atile + ((c) & 1) * 1024;                                     \
        _Pragma("unroll") for (int j = 0; j < 4; ++j) {                            \
            const int rowj = j * 8 + (lane >> 3);                                  \
            const float* src = xg0 + (size_t)rowj * DIMK + (c) * CHUNK             \
                               + (((lane & 7) ^ (rowj & 7)) << 2);                 \
            __builtin_amdgcn_global_load_lds(                                      \
                (const __attribute__((address_space(1))) void*)src,                \
                (__attribute__((address_space(3))) void*)(dst + j * 256),          \
                16, 0, 0);                                                         \
        }                                                                          \
    }

#define LOADW(u, slot)                                                             \
    {                                                                              \
        const int kg = kwb + (u) * KSTEP;                                          \
        wr[slot][0] = ldw(wsp, kg, half_, 0, 0, row);                              \
        wr[slot][1] = ldw(wsp, kg, half_, 0, 1, row);                              \
        wr[slot][2] = ldw(wsp, kg, half_, 1, 0, row);                              \
        wr[slot][3] = ldw(wsp, kg, half_, 1, 1, row);                              \
    }

    half8 wr[4][4];            // W ring: slot = u % 4 (static under chunk-pair unroll)
    f32x16 acc[2] = {};        // one accumulator per 32-expert tile

    // prologue issue order fixes the vmcnt ledger: W(0),W(1),W(2) [12], A(0)[4], A(1)[4]
    LOADW(0, 0);
    LOADW(1, 1);
    LOADW(2, 2);
    STAGE(0);
    STAGE(1);

    // chunk-pair loop keeps ring slot (u&3) and dbuf index compile-time static
    for (int cb = 0; cb < NCHUNK / 2; ++cb) {
#pragma unroll
        for (int pc = 0; pc < 2; ++pc) {
            const int c = 2 * cb + pc;              // c & 1 == pc (static)
            // fence: W(2c),W(2c+1) + STAGE(c) retired. Younger-than-W(2c+1) in the
            // in-order queue = the single next LOADW (4). Last chunk: drain all.
            if (cb == NCHUNK / 2 - 1 && pc == 1) {
                asm volatile("s_waitcnt vmcnt(0)" ::: "memory");
            } else {
                asm volatile("s_waitcnt vmcnt(4)" ::: "memory");
            }

            const float* buf = atile + pc * 1024;

            // ---- hoisted A-fragment ds_reads for both ksteps (XOR-swizzled granules) ----
            float4 fA[NKS], fB[NKS];
#pragma unroll
            for (int ks = 0; ks < NKS; ++ks) {
                const int g  = ks * 4 + half_ * 2;
                const int s0 = g ^ (row & 7);
                const int s1 = (g + 1) ^ (row & 7);
                fA[ks] = *(const float4*)&buf[row * 32 + s0 * 4];
                fB[ks] = *(const float4*)&buf[row * 32 + s1 * 4];
            }
            // buffer captured -> safe to restage this buffer
            asm volatile("s_waitcnt lgkmcnt(0)" ::: "memory");
            if (c + 2 < NCHUNK) STAGE(c + 2);

            // ---- 2 ksteps: W prefetch d=3 + limb conversion + 6 MFMAs ----
#pragma unroll
            for (int ks = 0; ks < NKS; ++ks) {
                const int u = c * NKS + ks;                  // = 4*cb + 2*pc + ks
                const int slot = (2 * pc + ks) & 3;          // u & 3 (static)
                if (u + 3 < NU) LOADW(u + 3, (slot + 3) & 3);

                const float4 va = fA[ks], vb = fB[ks];
                const float f[8] = {va.x, va.y, va.z, va.w, vb.x, vb.y, vb.z, vb.w};
                half8 a0, a1;
#pragma unroll
                for (int j = 0; j < 8; ++j) {
                    _Float16 h = (_Float16)f[j];
                    a0[j] = h;
                    a1[j] = (_Float16)(f[j] - (float)h);
                }

                const half8* w = wr[slot];
                acc[0] = __builtin_amdgcn_mfma_f32_32x32x16_f16(a0, w[0], acc[0], 0, 0, 0);
                acc[0] = __builtin_amdgcn_mfma_f32_32x32x16_f16(a1, w[0], acc[0], 0, 0, 0);
                acc[0] = __builtin_amdgcn_mfma_f32_32x32x16_f16(a0, w[1], acc[0], 0, 0, 0);
                acc[1] = __builtin_amdgcn_mfma_f32_32x32x16_f16(a0, w[2], acc[1], 0, 0, 0);
                acc[1] = __builtin_amdgcn_mfma_f32_32x32x16_f16(a1, w[2], acc[1], 0, 0, 0);
                acc[1] = __builtin_amdgcn_mfma_f32_32x32x16_f16(a0, w[3], acc[1], 0, 0, 0);
            }
        }
    }

    // ---------------- cross-wave K reduction (R2-validated) ----------------
    __syncthreads();
    float* red = lds;   // [wave][32 rows][68 pad] = 4 x 2176 floats
    // D frag (32x32): col = lane&31, rowD = (s&3) + 8*(s>>2) + 4*half_
#pragma unroll
    for (int s = 0; s < 16; ++s) {
        const int rowD = (s & 3) + 8 * (s >> 2) + 4 * half_;
        red[wv * 2176 + rowD * 68 + 0 * 32 + row] = acc[0][s];
        red[wv * 2176 + rowD * 68 + 1 * 32 + row] = acc[1][s];
    }
    __syncthreads();

    // ---------------- epilogue: bias + stable top-2 + softmax (validated path) ----------------
    {
        const int rr = t >> 3;   // 0..31 row within block
        const int g8 = t & 7;    // expert-group 0..7
        float l[8];
#pragma unroll
        for (int j = 0; j < 8; ++j) {
            float s = 0.f;
#pragma unroll
            for (int w2 = 0; w2 < NW; ++w2) s += red[w2 * 2176 + rr * 68 + g8 * 8 + j];
            l[j] = s + bias[g8 * 8 + j];
        }

        float v0 = l[0];
        int   i0 = 8 * g8;
        float v1 = -INFINITY;
        int   i1 = -1;
#pragma unroll
        for (int j = 1; j < 8; ++j) {
            const float lv = l[j];
            const int   e  = 8 * g8 + j;
            if (lv > v0) { v1 = v0; i1 = i0; v0 = lv; i0 = e; }
            else if (lv > v1) { v1 = lv; i1 = e; }
        }
#pragma unroll
        for (int m2 = 1; m2 <= 4; m2 <<= 1) {
            const float ov0 = __shfl_xor(v0, m2);
            const int   oi0 = __shfl_xor(i0, m2);
            const float ov1 = __shfl_xor(v1, m2);
            const int   oi1 = __shfl_xor(i1, m2);
            if (gt_pair(ov0, oi0, v0, i0)) {
                if (gt_pair(v0, i0, ov1, oi1)) { v1 = v0; i1 = i0; }
                else                           { v1 = ov1; i1 = oi1; }
                v0 = ov0; i0 = oi0;
            } else if (gt_pair(ov0, oi0, v1, i1)) {
                v1 = ov0; i1 = oi0;
            }
        }
        float d = 0.f;
#pragma unroll
        for (int j = 0; j < 8; ++j) d += expf(l[j] - v0);
#pragma unroll
        for (int m2 = 1; m2 <= 4; m2 <<= 1) d += __shfl_xor(d, m2);

        if (g8 == 0) {
            const int R = r0 + rr;
            out[2 * R]     = (float)i0;
            out[2 * R + 1] = (float)i1;
            out[2 * M + 2 * R]     = 1.f / d;
            out[2 * M + 2 * R + 1] = expf(v1 - v0) / d;
        }
    }
}

extern "C" void kernel_launch(void* const* d_in, const int* in_sizes, int n_in,
                              void* d_out, int out_size, void* d_ws, size_t ws_size,
                              hipStream_t stream) {
    const float* x  = (const float*)d_in[0];
    const float* W  = (const float*)d_in[1];
    const float* b  = (const float*)d_in[2];
    float* out = (float*)d_out;
    _Float16* ws = (_Float16*)d_ws;
    const int M = in_sizes[0] / DIMK;   // 16384 rows

    SwitchRouter_wsplit<<<(NEXP * DIMK + 255) / 256, 256, 0, stream>>>(W, ws);
    SwitchRouter_43078521979510_kernel<<<M / BM, 256, 0, stream>>>(x, ws, b, out, M);
}

// Round 12
// 33.432 us; speedup vs baseline: 1.3214x; 1.0160x over previous
//
#include <hip/hip_runtime.h>
#include <math.h>

typedef _Float16 half8 __attribute__((ext_vector_type(8)));
typedef float f32x16 __attribute__((ext_vector_type(16)));

#define DIMK 2048
#define NEXP 64
#define BM 32                 // rows per block
#define NW 4                  // waves per block (k-split)
#define KPW (DIMK / NW)       // 512 k per wave
#define CHUNK 32              // k per staged chunk (2 ksteps)
#define NCHUNK (KPW / CHUNK)  // 16 chunks per wave
#define KSTEP 16              // k per 32x32x16 MFMA step
#define NKS (CHUNK / KSTEP)   // 2 ksteps per chunk
#define NU (KPW / KSTEP)      // 32 ksteps total per wave

// ---------------- W pre-split kernel (R2-validated) ----------------
// ws layout (halfs): [kb8 = k/8][limb][e][k%8]  -> block of 512 halfs per (kb8,limb)
__global__ void SwitchRouter_wsplit(const float* __restrict__ W, _Float16* __restrict__ ws) {
    int t = blockIdx.x * 256 + threadIdx.x;
    if (t >= NEXP * DIMK) return;
    int e = t >> 11, k = t & (DIMK - 1);
    float w = W[e * DIMK + k];
    _Float16 h0 = (_Float16)w;
    _Float16 h1 = (_Float16)(w - (float)h0);
    int kb8 = k >> 3, kj = k & 7;
    ws[(((kb8 * 2 + 0) << 9) + (e << 3) + kj)] = h0;
    ws[(((kb8 * 2 + 1) << 9) + (e << 3) + kj)] = h1;
}

__device__ __forceinline__ bool gt_pair(float v, int i, float v2, int i2) {
    return (v > v2) || (v == v2 && i < i2);
}

__device__ __forceinline__ half8 ldw(const _Float16* wsp, int kglob0, int half_, int et, int limb, int row) {
    int kb8 = (kglob0 >> 3) + half_;
    return *(const half8*)(wsp + (((size_t)(kb8 * 2 + limb) << 9) + (((et << 5) + row) << 3)));
}

__global__ __launch_bounds__(256, 3)
void SwitchRouter_43078521979510_kernel(const float* __restrict__ x,
                                        const _Float16* __restrict__ wsp,
                                        const float* __restrict__ bias,
                                        float* __restrict__ out, int M)
{
    __shared__ float lds[8704];   // 34.8 KB: 4 waves x dbuf x (32 rows x 32 k); aliased by reduction (4x2176)

    const int t     = threadIdx.x;
    const int wv    = t >> 6;
    const int lane  = t & 63;
    const int row   = lane & 31;   // A row within tile / W expert within et-group
    const int half_ = lane >> 5;   // k sub-slice selector
    const int r0    = blockIdx.x * BM;
    const int kwb   = wv * KPW;

    float* atile = lds + wv * 2048;     // 2 bufs x 1024 floats
    const float* xg0 = x + (size_t)r0 * DIMK + kwb;

    // staging: instr j covers rows j*8+(lane>>3), granule lane&7 (XOR-swizzled vs row&7)
#define STAGE(c)                                                                   \
    {                                                                              \
        float* dst = atile + ((c) & 1) * 1024;                                     \
        _Pragma("unroll") for (int j = 0; j < 4; ++j) {                            \
            const int rowj = j * 8 + (lane >> 3);                                  \
            const float* src = xg0 + (size_t)rowj * DIMK + (c) * CHUNK             \
                               + (((lane & 7) ^ (rowj & 7)) << 2);                 \
            __builtin_amdgcn_global_load_lds(                                      \
                (const __attribute__((address_space(1))) void*)src,                \
                (__attribute__((address_space(3))) void*)(dst + j * 256),          \
                16, 0, 0);                                                         \
        }                                                                          \
    }

#define LOADW(u, slot)                                                             \
    {                                                                              \
        const int kg = kwb + (u) * KSTEP;                                          \
        wr[slot][0] = ldw(wsp, kg, half_, 0, 0, row);                              \
        wr[slot][1] = ldw(wsp, kg, half_, 0, 1, row);                              \
        wr[slot][2] = ldw(wsp, kg, half_, 1, 0, row);                              \
        wr[slot][3] = ldw(wsp, kg, half_, 1, 1, row);                              \
    }

    // one kstep: A limb conversion + 6 MFMAs against W ring slot (static)
#define KSTEP_DO(ks, slot)                                                         \
    {                                                                              \
        const float4 va = fA[ks], vb = fB[ks];                                     \
        const float f[8] = {va.x, va.y, va.z, va.w, vb.x, vb.y, vb.z, vb.w};       \
        half8 a0, a1;                                                              \
        _Pragma("unroll") for (int j = 0; j < 8; ++j) {                            \
            _Float16 h = (_Float16)f[j];                                           \
            a0[j] = h;                                                             \
            a1[j] = (_Float16)(f[j] - (float)h);                                   \
        }                                                                          \
        const half8* w = wr[slot];                                                 \
        acc[0] = __builtin_amdgcn_mfma_f32_32x32x16_f16(a0, w[0], acc[0], 0, 0, 0); \
        acc[0] = __builtin_amdgcn_mfma_f32_32x32x16_f16(a1, w[0], acc[0], 0, 0, 0); \
        acc[0] = __builtin_amdgcn_mfma_f32_32x32x16_f16(a0, w[1], acc[0], 0, 0, 0); \
        acc[1] = __builtin_amdgcn_mfma_f32_32x32x16_f16(a0, w[2], acc[1], 0, 0, 0); \
        acc[1] = __builtin_amdgcn_mfma_f32_32x32x16_f16(a1, w[2], acc[1], 0, 0, 0); \
        acc[1] = __builtin_amdgcn_mfma_f32_32x32x16_f16(a0, w[3], acc[1], 0, 0, 0); \
    }

    half8 wr[4][4];            // W ring: slot = u % 4 (static under chunk-pair unroll)
    f32x16 acc[2] = {};        // one accumulator per 32-expert tile

    // prologue issue order (fixes the vmcnt ledger): W0[4], W1[4], S0[4], W2[4], S1[4]
    LOADW(0, 0);
    LOADW(1, 1);
    STAGE(0);
    LOADW(2, 2);
    STAGE(1);

    // chunk-pair loop keeps ring slot and dbuf index compile-time static.
    // Per-iteration VMEM issue order: W(2c+3) | S(c+2) | W(2c+4)
    // Fence c needs S(c), W(2c), W(2c+1); youngest required = W(2c+3-... ) = W(2c+1),
    // first issue of iter c-1 -> leave S(c+1)+W(2c+2) = vmcnt(8). Last chunk: drain.
    for (int cb = 0; cb < NCHUNK / 2; ++cb) {
#pragma unroll
        for (int pc = 0; pc < 2; ++pc) {
            const int c = 2 * cb + pc;              // c & 1 == pc (static)
            if (cb == NCHUNK / 2 - 1 && pc == 1) {
                asm volatile("s_waitcnt vmcnt(0)" ::: "memory");
            } else {
                asm volatile("s_waitcnt vmcnt(8)" ::: "memory");
            }

            const float* buf = atile + pc * 1024;

            // ---- hoisted A-fragment ds_reads for both ksteps (XOR-swizzled granules) ----
            float4 fA[NKS], fB[NKS];
#pragma unroll
            for (int ks = 0; ks < NKS; ++ks) {
                const int g  = ks * 4 + half_ * 2;
                const int s0 = g ^ (row & 7);
                const int s1 = (g + 1) ^ (row & 7);
                fA[ks] = *(const float4*)&buf[row * 32 + s0 * 4];
                fB[ks] = *(const float4*)&buf[row * 32 + s1 * 4];
            }

            // W prefetch for kstep1 of chunk c+1 (slot (2pc+3)&3: pc=0 -> 3, pc=1 -> 1)
            if (2 * c + 3 < NU) LOADW(2 * c + 3, (2 * pc + 3) & 3);

            // buffer captured -> safe to restage this buffer
            asm volatile("s_waitcnt lgkmcnt(0)" ::: "memory");
            if (c + 2 < NCHUNK) STAGE(c + 2);

            // kstep 0: uses slot (2pc)&3 (pc=0 -> 0, pc=1 -> 2)
            KSTEP_DO(0, (2 * pc) & 3);

            // W prefetch for kstep0 of chunk c+2 -> reuses the slot kstep0 just consumed
            if (2 * c + 4 < NU) LOADW(2 * c + 4, (2 * pc + 4) & 3);

            // kstep 1: uses slot (2pc+1)&3 (pc=0 -> 1, pc=1 -> 3)
            KSTEP_DO(1, (2 * pc + 1) & 3);
        }
    }

    // ---------------- cross-wave K reduction (R2-validated) ----------------
    __syncthreads();
    float* red = lds;   // [wave][32 rows][68 pad] = 4 x 2176 floats
    // D frag (32x32): col = lane&31, rowD = (s&3) + 8*(s>>2) + 4*half_
#pragma unroll
    for (int s = 0; s < 16; ++s) {
        const int rowD = (s & 3) + 8 * (s >> 2) + 4 * half_;
        red[wv * 2176 + rowD * 68 + 0 * 32 + row] = acc[0][s];
        red[wv * 2176 + rowD * 68 + 1 * 32 + row] = acc[1][s];
    }
    __syncthreads();

    // ---------------- epilogue: bias + stable top-2 + softmax (validated path) ----------------
    {
        const int rr = t >> 3;   // 0..31 row within block
        const int g8 = t & 7;    // expert-group 0..7
        float l[8];
#pragma unroll
        for (int j = 0; j < 8; ++j) {
            float s = 0.f;
#pragma unroll
            for (int w2 = 0; w2 < NW; ++w2) s += red[w2 * 2176 + rr * 68 + g8 * 8 + j];
            l[j] = s + bias[g8 * 8 + j];
        }

        float v0 = l[0];
        int   i0 = 8 * g8;
        float v1 = -INFINITY;
        int   i1 = -1;
#pragma unroll
        for (int j = 1; j < 8; ++j) {
            const float lv = l[j];
            const int   e  = 8 * g8 + j;
            if (lv > v0) { v1 = v0; i1 = i0; v0 = lv; i0 = e; }
            else if (lv > v1) { v1 = lv; i1 = e; }
        }
#pragma unroll
        for (int m2 = 1; m2 <= 4; m2 <<= 1) {
            const float ov0 = __shfl_xor(v0, m2);
            const int   oi0 = __shfl_xor(i0, m2);
            const float ov1 = __shfl_xor(v1, m2);
            const int   oi1 = __shfl_xor(i1, m2);
            if (gt_pair(ov0, oi0, v0, i0)) {
                if (gt_pair(v0, i0, ov1, oi1)) { v1 = v0; i1 = i0; }
                else                           { v1 = ov1; i1 = oi1; }
                v0 = ov0; i0 = oi0;
            } else if (gt_pair(ov0, oi0, v1, i1)) {
                v1 = ov0; i1 = oi0;
            }
        }
        float d = 0.f;
#pragma unroll
        for (int j = 0; j < 8; ++j) d += expf(l[j] - v0);
#pragma unroll
        for (int m2 = 1; m2 <= 4; m2 <<= 1) d += __shfl_xor(d, m2);

        if (g8 == 0) {
            const int R = r0 + rr;
            out[2 * R]     = (float)i0;
            out[2 * R + 1] = (float)i1;
            out[2 * M + 2 * R]     = 1.f / d;
            out[2 * M + 2 * R + 1] = expf(v1 - v0) / d;
        }
    }
}

extern "C" void kernel_launch(void* const* d_in, const int* in_sizes, int n_in,
                              void* d_out, int out_size, void* d_ws, size_t ws_size,
                              hipStream_t stream) {
    const float* x  = (const float*)d_in[0];
    const float* W  = (const float*)d_in[1];
    const float* b  = (const float*)d_in[2];
    float* out = (float*)d_out;
    _Float16* ws = (_Float16*)d_ws;
    const int M = in_sizes[0] / DIMK;   // 16384 rows

    SwitchRouter_wsplit<<<(NEXP * DIMK + 255) / 256, 256, 0, stream>>>(W, ws);
    SwitchRouter_43078521979510_kernel<<<M / BM, 256, 0, stream>>>(x, ws, b, out, M);
}